// Round 1
// baseline (612.233 us; speedup 1.0000x reference)
//
#include <hip/hip_runtime.h>
#include <hip/hip_bf16.h>

// Problem: Mamba block (B=1, L=4096, D=256, d_inner=512, d_state=16, dt_rank=16,
// d_conv=4) + 3 sequential policy-MLP steps. All fp32. Output (3,4096,7).

#define L_SEQ   4096
#define D_MODEL 256
#define D_INNER 512
#define D_STATE 16
#define DT_RANK 16
#define N_CHUNK 64     // 64 chunks of 64 steps

__device__ __forceinline__ float softplus_f(float x) {
    return fmaxf(x, 0.f) + log1pf(__expf(-fabsf(x)));
}

// ---------------- rmsnorm: one block per row, D=256 ----------------
__global__ __launch_bounds__(256) void rmsnorm_k(const float* __restrict__ x,
                                                 const float* __restrict__ w,
                                                 float* __restrict__ o) {
    __shared__ float red[256];
    int row = blockIdx.x, t = threadIdx.x;
    float v = x[row * 256 + t];
    red[t] = v * v;
    __syncthreads();
    for (int s = 128; s > 0; s >>= 1) {
        if (t < s) red[t] += red[t + s];
        __syncthreads();
    }
    float rms = rsqrtf(red[0] / 256.f + 1e-5f);
    o[row * 256 + t] = v * rms * w[t];
}

// ---------------- generic fp32 GEMM: C[M,N] = act(A[M,K] * B[N,K]^T + bias + res) ----------------
// BM=BN=64, BK=16, 256 threads, 4x4 micro-tile per thread.
#define BM 64
#define BN 64
#define BK 16
__global__ __launch_bounds__(256) void gemm_bt(
    const float* __restrict__ A, int lda,
    const float* __restrict__ B, int ldb,
    float* __restrict__ C, int ldc,
    int M, int N, int K,
    const float* __restrict__ bias,
    const float* __restrict__ res,
    int act)  // 0=none, 1=leaky_relu(0.1), 2=softplus
{
    __shared__ __align__(16) float As[BK][BM + 4];
    __shared__ __align__(16) float Bs[BK][BN + 4];
    int t = threadIdx.x;
    int tx = t & 15, ty = t >> 4;
    int m0 = blockIdx.x * BM, n0 = blockIdx.y * BN;
    float acc[4][4] = {};
    int kk = t & 15;   // k within tile (load phase)
    int lr = t >> 4;   // base row (load phase)
    for (int k0 = 0; k0 < K; k0 += BK) {
        int gk = k0 + kk;
        bool kok = gk < K;
#pragma unroll
        for (int i = 0; i < 4; i++) {
            int row = lr + i * 16;
            int gm = m0 + row;
            As[kk][row] = (kok && gm < M) ? A[(long)gm * lda + gk] : 0.f;
            int gn = n0 + row;
            Bs[kk][row] = (kok && gn < N) ? B[(long)gn * ldb + gk] : 0.f;
        }
        __syncthreads();
#pragma unroll
        for (int k = 0; k < BK; k++) {
            float4 a4 = *(const float4*)&As[k][ty * 4];
            float4 b4 = *(const float4*)&Bs[k][tx * 4];
            float a[4] = {a4.x, a4.y, a4.z, a4.w};
            float b[4] = {b4.x, b4.y, b4.z, b4.w};
#pragma unroll
            for (int i = 0; i < 4; i++)
#pragma unroll
                for (int j = 0; j < 4; j++) acc[i][j] += a[i] * b[j];
        }
        __syncthreads();
    }
#pragma unroll
    for (int i = 0; i < 4; i++) {
        int m = m0 + ty * 4 + i;
        if (m >= M) continue;
#pragma unroll
        for (int j = 0; j < 4; j++) {
            int n = n0 + tx * 4 + j;
            if (n >= N) continue;
            float v = acc[i][j];
            if (bias) v += bias[n];
            if (res)  v += res[(long)m * ldc + n];
            if (act == 1) v = v > 0.f ? v : 0.1f * v;
            else if (act == 2) v = softplus_f(v);
            C[(long)m * ldc + n] = v;
        }
    }
}

// ---------------- causal depthwise conv (d_conv=4) + silu ----------------
__global__ __launch_bounds__(256) void conv_silu(const float* __restrict__ xz,
                                                 const float* __restrict__ W,
                                                 const float* __restrict__ b,
                                                 float* __restrict__ xc) {
    int t = blockIdx.x * 256 + threadIdx.x;  // l*512 + e
    int l = t >> 9, e = t & 511;
    float acc = b[e];
#pragma unroll
    for (int k = 0; k < 4; k++) {
        int ll = l - 3 + k;
        float xv = (ll >= 0) ? xz[ll * 1024 + e] : 0.f;
        acc += W[e * 4 + k] * xv;
    }
    float sig = 1.f / (1.f + __expf(-acc));
    xc[t] = acc * sig;
}

// ---------------- chunked parallel scan ----------------
// Phase A: per chunk, per (d,n): P = prod(exp(dt*A)), S = local final state (s0=0)
__global__ __launch_bounds__(256) void scan_phaseA(const float* __restrict__ delta,
                                                   const float* __restrict__ xc,
                                                   const float* __restrict__ dbc,
                                                   const float* __restrict__ A_log,
                                                   float* __restrict__ P,
                                                   float* __restrict__ S) {
    int n = threadIdx.x & 15, dl = threadIdx.x >> 4;
    int d = blockIdx.y * 16 + dl;
    int c = blockIdx.x;
    float Ad = -__expf(A_log[d * 16 + n]);
    float p = 1.f, s = 0.f;
    int l0 = c * 64;
    for (int i = 0; i < 64; i++) {
        int l = l0 + i;
        float dt = delta[l * 512 + d];
        float xv = xc[l * 512 + d];
        float b = dbc[l * 48 + 16 + n];
        float a = __expf(dt * Ad);
        p *= a;
        s = a * s + dt * b * xv;
    }
    int idx = (c * 512 + d) * 16 + n;
    P[idx] = p;
    S[idx] = s;
}

// Phase B: sequential combine over chunks; carry[c] = state entering chunk c
__global__ __launch_bounds__(256) void scan_phaseB(const float* __restrict__ P,
                                                   const float* __restrict__ S,
                                                   float* __restrict__ carry) {
    int t = blockIdx.x * 256 + threadIdx.x;  // d*16+n, 0..8191
    float h = 0.f;
    for (int c = 0; c < N_CHUNK; c++) {
        carry[c * 8192 + t] = h;
        h = P[c * 8192 + t] * h + S[c * 8192 + t];
    }
}

// Phase C: replay chunk with correct carry; y[l,d] = (sum_n s*C + xc*Dp) * silu(z)
__global__ __launch_bounds__(256) void scan_phaseC(const float* __restrict__ delta,
                                                   const float* __restrict__ xc,
                                                   const float* __restrict__ dbc,
                                                   const float* __restrict__ A_log,
                                                   const float* __restrict__ carry,
                                                   const float* __restrict__ xz,
                                                   const float* __restrict__ Dp,
                                                   float* __restrict__ y) {
    int n = threadIdx.x & 15, dl = threadIdx.x >> 4;
    int d = blockIdx.y * 16 + dl;
    int c = blockIdx.x;
    float Ad = -__expf(A_log[d * 16 + n]);
    float s = carry[(c * 512 + d) * 16 + n];
    float dp = Dp[d];
    int l0 = c * 64;
    for (int i = 0; i < 64; i++) {
        int l = l0 + i;
        float dt = delta[l * 512 + d];
        float xv = xc[l * 512 + d];
        float b = dbc[l * 48 + 16 + n];
        float cc = dbc[l * 48 + 32 + n];
        float a = __expf(dt * Ad);
        s = a * s + dt * b * xv;
        float contrib = s * cc;
        contrib += __shfl_xor(contrib, 8, 16);
        contrib += __shfl_xor(contrib, 4, 16);
        contrib += __shfl_xor(contrib, 2, 16);
        contrib += __shfl_xor(contrib, 1, 16);
        if (n == 0) {
            float z = xz[l * 1024 + 512 + d];
            float sig = 1.f / (1.f + __expf(-z));
            y[l * 512 + d] = (contrib + xv * dp) * (z * sig);
        }
    }
}

// ---------------- softmax(y_init) + pack combined = [feats | y_t] (stride 264) ----------------
__global__ __launch_bounds__(256) void softmax_pack(const float* __restrict__ feats,
                                                    const float* __restrict__ logits,
                                                    float* __restrict__ comb) {
    int t = blockIdx.x * 256 + threadIdx.x;  // 0 .. 4096*264
    int row = t / 264, col = t % 264;
    if (col < 256) {
        comb[row * 264 + col] = feats[row * 256 + col];
    } else if (col < 263) {
        int c = col - 256;
        float v[7], m = -1e30f;
#pragma unroll
        for (int i = 0; i < 7; i++) { v[i] = logits[row * 7 + i]; m = fmaxf(m, v[i]); }
        float sum = 0.f;
#pragma unroll
        for (int i = 0; i < 7; i++) sum += __expf(v[i] - m);
        comb[row * 264 + col] = __expf(v[c] - m) / sum;
    }
}

// ---------------- mu/var heads + action update; writes y_t into comb tail and d_out ----------------
__global__ __launch_bounds__(256) void mlp_update(const float* __restrict__ h2,
                                                  const float* __restrict__ muW,
                                                  const float* __restrict__ mub,
                                                  const float* __restrict__ varW,
                                                  const float* __restrict__ varb,
                                                  const float* __restrict__ eps,
                                                  float* __restrict__ comb,
                                                  float* __restrict__ out,
                                                  int step) {
    int t = blockIdx.x * 256 + threadIdx.x;
    if (t >= 4096 * 7) return;
    int row = t / 7, c = t % 7;
    const float* hr = h2 + row * 128;
    float mu = mub[c], va = varb[c];
    for (int k = 0; k < 128; k++) {
        float h = hr[k];
        mu += h * muW[c * 128 + k];
        va += h * varW[c * 128 + k];
    }
    float sp = softplus_f(va);
    float e = eps[(step * 4096 + row) * 7 + c];
    float yo = comb[row * 264 + 256 + c];
    float yn = yo - (mu + sp * e);
    out[(step * 4096 + row) * 7 + c] = yn;
    comb[row * 264 + 256 + c] = yn;
}

extern "C" void kernel_launch(void* const* d_in, const int* in_sizes, int n_in,
                              void* d_out, int out_size, void* d_ws, size_t ws_size,
                              hipStream_t stream) {
    const float* features  = (const float*)d_in[0];
    const float* y_init    = (const float*)d_in[1];
    const float* eps       = (const float*)d_in[2];
    const float* in_proj_W = (const float*)d_in[3];
    const float* conv_W    = (const float*)d_in[4];
    const float* conv_b    = (const float*)d_in[5];
    const float* x_proj_W  = (const float*)d_in[6];
    const float* dt_proj_W = (const float*)d_in[7];
    const float* dt_proj_b = (const float*)d_in[8];
    const float* A_log     = (const float*)d_in[9];
    const float* Dp        = (const float*)d_in[10];
    const float* out_proj_W= (const float*)d_in[11];
    const float* norm_w    = (const float*)d_in[12];
    const float* norm_f_w  = (const float*)d_in[13];
    const float* lm_head_W = (const float*)d_in[14];
    const float* fn1_W     = (const float*)d_in[15];
    const float* fn1_b     = (const float*)d_in[16];
    const float* fn2_W     = (const float*)d_in[17];
    const float* fn2_b     = (const float*)d_in[18];
    const float* mu_W      = (const float*)d_in[19];
    const float* mu_b      = (const float*)d_in[20];
    const float* var_W     = (const float*)d_in[21];
    const float* var_b     = (const float*)d_in[22];
    float* out = (float*)d_out;
    float* ws  = (float*)d_ws;

    // workspace layout (floats); total ~13.3M floats (~51 MB)
    float* h     = ws;                    // 4096*256
    float* xz    = ws + 1048576;          // 4096*1024
    float* xc    = ws + 5242880;          // 4096*512
    float* dbc   = ws + 7340032;          // 4096*48
    float* delta = ws + 7536640;          // 4096*512
    float* outp  = delta;                 // reuse after scan (4096*256)
    float* xf    = delta + 1048576;       // (4096*256)
    float* P     = ws + 9633792;          // 64*512*16
    float* S     = ws + 10158080;         // 64*512*16
    float* feats = P;                     // reuse after scan (4096*256)
    float* carry = ws + 10682368;         // 64*512*16
    float* y     = ws + 11206656;         // 4096*512
    float* comb  = y;                     // reuse after out_proj (4096*264)
    float* h1    = h;                     // reuse (4096*128)
    float* h2    = h + 524288;            // (4096*128)

    // ---- Mamba block ----
    rmsnorm_k<<<4096, 256, 0, stream>>>(features, norm_w, h);
    gemm_bt<<<dim3(64, 16), 256, 0, stream>>>(h, 256, in_proj_W, 256, xz, 1024,
                                              4096, 1024, 256, nullptr, nullptr, 0);
    conv_silu<<<8192, 256, 0, stream>>>(xz, conv_W, conv_b, xc);
    gemm_bt<<<dim3(64, 1), 256, 0, stream>>>(xc, 512, x_proj_W, 512, dbc, 48,
                                             4096, 48, 512, nullptr, nullptr, 0);
    gemm_bt<<<dim3(64, 8), 256, 0, stream>>>(dbc, 48, dt_proj_W, 16, delta, 512,
                                             4096, 512, 16, dt_proj_b, nullptr, 2);
    scan_phaseA<<<dim3(64, 32), 256, 0, stream>>>(delta, xc, dbc, A_log, P, S);
    scan_phaseB<<<32, 256, 0, stream>>>(P, S, carry);
    scan_phaseC<<<dim3(64, 32), 256, 0, stream>>>(delta, xc, dbc, A_log, carry, xz, Dp, y);
    gemm_bt<<<dim3(64, 4), 256, 0, stream>>>(y, 512, out_proj_W, 512, outp, 256,
                                             4096, 256, 512, nullptr, features, 0);
    rmsnorm_k<<<4096, 256, 0, stream>>>(outp, norm_f_w, xf);
    gemm_bt<<<dim3(64, 4), 256, 0, stream>>>(xf, 256, lm_head_W, 256, feats, 256,
                                             4096, 256, 256, nullptr, nullptr, 0);

    // ---- policy MLP steps ----
    softmax_pack<<<4224, 256, 0, stream>>>(feats, y_init, comb);
    for (int s = 0; s < 3; s++) {
        gemm_bt<<<dim3(64, 2), 256, 0, stream>>>(comb, 264, fn1_W, 263, h1, 128,
                                                 4096, 128, 263, fn1_b, nullptr, 1);
        gemm_bt<<<dim3(64, 2), 256, 0, stream>>>(h1, 128, fn2_W, 128, h2, 128,
                                                 4096, 128, 128, fn2_b, nullptr, 1);
        mlp_update<<<112, 256, 0, stream>>>(h2, mu_W, mu_b, var_W, var_b, eps, comb, out, s);
    }
}

// Round 2
// 379.945 us; speedup vs baseline: 1.6114x; 1.6114x over previous
//
#include <hip/hip_runtime.h>
#include <hip/hip_bf16.h>

// Mamba block (B=1, L=4096, D=256, d_inner=512, d_state=16, dt_rank=16, d_conv=4)
// + 3 sequential policy-MLP steps. fp32 in/out; GEMMs internally bf16-MFMA.

#define N_CHUNK 64

typedef __bf16 bf16_t;
typedef __attribute__((ext_vector_type(8))) __bf16 bf16x8;
typedef __attribute__((ext_vector_type(4))) float f32x4;

__device__ __forceinline__ float softplus_f(float x) {
    return fmaxf(x, 0.f) + log1pf(__expf(-fabsf(x)));
}

// ---------------- rmsnorm: one block per row, D=256 ----------------
__global__ __launch_bounds__(256) void rmsnorm_k(const float* __restrict__ x,
                                                 const float* __restrict__ w,
                                                 float* __restrict__ o) {
    __shared__ float red[256];
    int row = blockIdx.x, t = threadIdx.x;
    float v = x[row * 256 + t];
    red[t] = v * v;
    __syncthreads();
    for (int s = 128; s > 0; s >>= 1) {
        if (t < s) red[t] += red[t + s];
        __syncthreads();
    }
    float rms = rsqrtf(red[0] / 256.f + 1e-5f);
    o[row * 256 + t] = v * rms * w[t];
}

// ---------------- bf16-MFMA GEMM: C[M,N] = act(A[M,K]*B[N,K]^T + bias + res) ----------------
// 64x64 tile, BK=32, 256 threads = 4 waves in 2x2, each wave 32x32 (2x2 16x16 frags).
// LDS stride 40 bf16 (80B = 20 banks) -> fragment b128 reads spread all 32 banks.
#define TM 64
#define TN 64
#define TK 32
#define LDSS 40
__global__ __launch_bounds__(256) void gemm_mfma(
    const float* __restrict__ A, int lda,
    const float* __restrict__ B, int ldb,
    float* __restrict__ C, int ldc,
    int M, int N, int K,
    const float* __restrict__ bias,
    const float* __restrict__ res,
    int act)  // 0=none, 1=leaky_relu(0.1), 2=softplus
{
    __shared__ __align__(16) bf16_t As[TM * LDSS];
    __shared__ __align__(16) bf16_t Bs[TN * LDSS];
    int t = threadIdx.x;
    int lane = t & 63, wave = t >> 6;
    int wm = wave & 1, wn = wave >> 1;     // 2x2 wave grid
    int fr = lane & 15;                    // frag row/col within 16
    int quad = lane >> 4;                  // k-block of 8
    int sr = t >> 2;                       // staging row 0..63
    int sc = t & 3;                        // staging col-block of 8
    int m0 = blockIdx.x * TM, n0 = blockIdx.y * TN;

    f32x4 acc[2][2] = {};

    for (int k0 = 0; k0 < K; k0 += TK) {
        // ---- stage A tile (fp32 -> bf16) ----
        {
            int gm = m0 + sr;
            long base = (long)gm * lda + k0 + sc * 8;
            float v[8];
            if (gm < M && (k0 + sc * 8 + 8) <= K && ((base & 3) == 0)) {
                float4 p0 = *(const float4*)(A + base);
                float4 p1 = *(const float4*)(A + base + 4);
                v[0]=p0.x; v[1]=p0.y; v[2]=p0.z; v[3]=p0.w;
                v[4]=p1.x; v[5]=p1.y; v[6]=p1.z; v[7]=p1.w;
            } else {
#pragma unroll
                for (int j = 0; j < 8; j++) {
                    int gk = k0 + sc * 8 + j;
                    v[j] = (gm < M && gk < K) ? A[(long)gm * lda + gk] : 0.f;
                }
            }
            bf16x8 pk;
#pragma unroll
            for (int j = 0; j < 8; j++) pk[j] = (bf16_t)v[j];
            *(bf16x8*)&As[sr * LDSS + sc * 8] = pk;
        }
        // ---- stage B tile ----
        {
            int gn = n0 + sr;
            long base = (long)gn * ldb + k0 + sc * 8;
            float v[8];
            if (gn < N && (k0 + sc * 8 + 8) <= K && ((base & 3) == 0)) {
                float4 p0 = *(const float4*)(B + base);
                float4 p1 = *(const float4*)(B + base + 4);
                v[0]=p0.x; v[1]=p0.y; v[2]=p0.z; v[3]=p0.w;
                v[4]=p1.x; v[5]=p1.y; v[6]=p1.z; v[7]=p1.w;
            } else {
#pragma unroll
                for (int j = 0; j < 8; j++) {
                    int gk = k0 + sc * 8 + j;
                    v[j] = (gn < N && gk < K) ? B[(long)gn * ldb + gk] : 0.f;
                }
            }
            bf16x8 pk;
#pragma unroll
            for (int j = 0; j < 8; j++) pk[j] = (bf16_t)v[j];
            *(bf16x8*)&Bs[sr * LDSS + sc * 8] = pk;
        }
        __syncthreads();
        // ---- MFMA: A frag = A[m=fr][k=quad*8+j], B frag mirrored ----
        bf16x8 af0 = *(bf16x8*)&As[(wm * 32 + fr) * LDSS + quad * 8];
        bf16x8 af1 = *(bf16x8*)&As[(wm * 32 + 16 + fr) * LDSS + quad * 8];
        bf16x8 bf0 = *(bf16x8*)&Bs[(wn * 32 + fr) * LDSS + quad * 8];
        bf16x8 bf1 = *(bf16x8*)&Bs[(wn * 32 + 16 + fr) * LDSS + quad * 8];
        acc[0][0] = __builtin_amdgcn_mfma_f32_16x16x32_bf16(af0, bf0, acc[0][0], 0, 0, 0);
        acc[0][1] = __builtin_amdgcn_mfma_f32_16x16x32_bf16(af0, bf1, acc[0][1], 0, 0, 0);
        acc[1][0] = __builtin_amdgcn_mfma_f32_16x16x32_bf16(af1, bf0, acc[1][0], 0, 0, 0);
        acc[1][1] = __builtin_amdgcn_mfma_f32_16x16x32_bf16(af1, bf1, acc[1][1], 0, 0, 0);
        __syncthreads();
    }

    // ---- epilogue: C/D layout col=lane&15, row=quad*4+reg ----
#pragma unroll
    for (int mi = 0; mi < 2; mi++) {
#pragma unroll
        for (int ni = 0; ni < 2; ni++) {
#pragma unroll
            for (int r = 0; r < 4; r++) {
                int m = m0 + wm * 32 + mi * 16 + quad * 4 + r;
                int n = n0 + wn * 32 + ni * 16 + fr;
                if (m < M && n < N) {
                    float v = acc[mi][ni][r];
                    if (bias) v += bias[n];
                    if (res)  v += res[(long)m * ldc + n];
                    if (act == 1) v = v > 0.f ? v : 0.1f * v;
                    else if (act == 2) v = softplus_f(v);
                    C[(long)m * ldc + n] = v;
                }
            }
        }
    }
}

// ---------------- causal depthwise conv (d_conv=4) + silu ----------------
__global__ __launch_bounds__(256) void conv_silu(const float* __restrict__ xz,
                                                 const float* __restrict__ W,
                                                 const float* __restrict__ b,
                                                 float* __restrict__ xc) {
    int t = blockIdx.x * 256 + threadIdx.x;  // l*512 + e
    int l = t >> 9, e = t & 511;
    float acc = b[e];
#pragma unroll
    for (int k = 0; k < 4; k++) {
        int ll = l - 3 + k;
        float xv = (ll >= 0) ? xz[ll * 1024 + e] : 0.f;
        acc += W[e * 4 + k] * xv;
    }
    float sig = 1.f / (1.f + __expf(-acc));
    xc[t] = acc * sig;
}

// ---------------- chunked parallel scan ----------------
__global__ __launch_bounds__(256) void scan_phaseA(const float* __restrict__ delta,
                                                   const float* __restrict__ xc,
                                                   const float* __restrict__ dbc,
                                                   const float* __restrict__ A_log,
                                                   float* __restrict__ P,
                                                   float* __restrict__ S) {
    int n = threadIdx.x & 15, dl = threadIdx.x >> 4;
    int d = blockIdx.y * 16 + dl;
    int c = blockIdx.x;
    float Ad = -__expf(A_log[d * 16 + n]);
    float p = 1.f, s = 0.f;
    int l0 = c * 64;
    for (int i = 0; i < 64; i++) {
        int l = l0 + i;
        float dt = delta[l * 512 + d];
        float xv = xc[l * 512 + d];
        float b = dbc[l * 48 + 16 + n];
        float a = __expf(dt * Ad);
        p *= a;
        s = a * s + dt * b * xv;
    }
    int idx = (c * 512 + d) * 16 + n;
    P[idx] = p;
    S[idx] = s;
}

__global__ __launch_bounds__(256) void scan_phaseB(const float* __restrict__ P,
                                                   const float* __restrict__ S,
                                                   float* __restrict__ carry) {
    int t = blockIdx.x * 256 + threadIdx.x;  // d*16+n
    float h = 0.f;
    for (int c = 0; c < N_CHUNK; c++) {
        carry[c * 8192 + t] = h;
        h = P[c * 8192 + t] * h + S[c * 8192 + t];
    }
}

__global__ __launch_bounds__(256) void scan_phaseC(const float* __restrict__ delta,
                                                   const float* __restrict__ xc,
                                                   const float* __restrict__ dbc,
                                                   const float* __restrict__ A_log,
                                                   const float* __restrict__ carry,
                                                   const float* __restrict__ xz,
                                                   const float* __restrict__ Dp,
                                                   float* __restrict__ y) {
    int n = threadIdx.x & 15, dl = threadIdx.x >> 4;
    int d = blockIdx.y * 16 + dl;
    int c = blockIdx.x;
    float Ad = -__expf(A_log[d * 16 + n]);
    float s = carry[(c * 512 + d) * 16 + n];
    float dp = Dp[d];
    int l0 = c * 64;
    for (int i = 0; i < 64; i++) {
        int l = l0 + i;
        float dt = delta[l * 512 + d];
        float xv = xc[l * 512 + d];
        float b = dbc[l * 48 + 16 + n];
        float cc = dbc[l * 48 + 32 + n];
        float a = __expf(dt * Ad);
        s = a * s + dt * b * xv;
        float contrib = s * cc;
        contrib += __shfl_xor(contrib, 8, 16);
        contrib += __shfl_xor(contrib, 4, 16);
        contrib += __shfl_xor(contrib, 2, 16);
        contrib += __shfl_xor(contrib, 1, 16);
        if (n == 0) {
            float z = xz[l * 1024 + 512 + d];
            float sig = 1.f / (1.f + __expf(-z));
            y[l * 512 + d] = (contrib + xv * dp) * (z * sig);
        }
    }
}

// ---------------- softmax(y_init) + pack combined = [feats | y_t] (stride 264) ----------------
__global__ __launch_bounds__(256) void softmax_pack(const float* __restrict__ feats,
                                                    const float* __restrict__ logits,
                                                    float* __restrict__ comb) {
    int t = blockIdx.x * 256 + threadIdx.x;
    int row = t / 264, col = t % 264;
    if (col < 256) {
        comb[row * 264 + col] = feats[row * 256 + col];
    } else if (col < 263) {
        int c = col - 256;
        float v[7], m = -1e30f;
#pragma unroll
        for (int i = 0; i < 7; i++) { v[i] = logits[row * 7 + i]; m = fmaxf(m, v[i]); }
        float sum = 0.f;
#pragma unroll
        for (int i = 0; i < 7; i++) sum += __expf(v[i] - m);
        comb[row * 264 + col] = __expf(v[c] - m) / sum;
    }
}

// ---------------- mu/var heads + action update ----------------
__global__ __launch_bounds__(256) void mlp_update(const float* __restrict__ h2,
                                                  const float* __restrict__ muW,
                                                  const float* __restrict__ mub,
                                                  const float* __restrict__ varW,
                                                  const float* __restrict__ varb,
                                                  const float* __restrict__ eps,
                                                  float* __restrict__ comb,
                                                  float* __restrict__ out,
                                                  int step) {
    int t = blockIdx.x * 256 + threadIdx.x;
    if (t >= 4096 * 7) return;
    int row = t / 7, c = t % 7;
    const float* hr = h2 + row * 128;
    float mu = mub[c], va = varb[c];
    for (int k = 0; k < 128; k++) {
        float h = hr[k];
        mu += h * muW[c * 128 + k];
        va += h * varW[c * 128 + k];
    }
    float sp = softplus_f(va);
    float e = eps[(step * 4096 + row) * 7 + c];
    float yo = comb[row * 264 + 256 + c];
    float yn = yo - (mu + sp * e);
    out[(step * 4096 + row) * 7 + c] = yn;
    comb[row * 264 + 256 + c] = yn;
}

extern "C" void kernel_launch(void* const* d_in, const int* in_sizes, int n_in,
                              void* d_out, int out_size, void* d_ws, size_t ws_size,
                              hipStream_t stream) {
    const float* features  = (const float*)d_in[0];
    const float* y_init    = (const float*)d_in[1];
    const float* eps       = (const float*)d_in[2];
    const float* in_proj_W = (const float*)d_in[3];
    const float* conv_W    = (const float*)d_in[4];
    const float* conv_b    = (const float*)d_in[5];
    const float* x_proj_W  = (const float*)d_in[6];
    const float* dt_proj_W = (const float*)d_in[7];
    const float* dt_proj_b = (const float*)d_in[8];
    const float* A_log     = (const float*)d_in[9];
    const float* Dp        = (const float*)d_in[10];
    const float* out_proj_W= (const float*)d_in[11];
    const float* norm_w    = (const float*)d_in[12];
    const float* norm_f_w  = (const float*)d_in[13];
    const float* lm_head_W = (const float*)d_in[14];
    const float* fn1_W     = (const float*)d_in[15];
    const float* fn1_b     = (const float*)d_in[16];
    const float* fn2_W     = (const float*)d_in[17];
    const float* fn2_b     = (const float*)d_in[18];
    const float* mu_W      = (const float*)d_in[19];
    const float* mu_b      = (const float*)d_in[20];
    const float* var_W     = (const float*)d_in[21];
    const float* var_b     = (const float*)d_in[22];
    float* out = (float*)d_out;
    float* ws  = (float*)d_ws;

    float* h     = ws;                    // 4096*256
    float* xz    = ws + 1048576;          // 4096*1024
    float* xc    = ws + 5242880;          // 4096*512
    float* dbc   = ws + 7340032;          // 4096*48
    float* delta = ws + 7536640;          // 4096*512
    float* outp  = delta;                 // reuse after scan (4096*256)
    float* xf    = delta + 1048576;       // (4096*256)
    float* P     = ws + 9633792;          // 64*512*16
    float* S     = ws + 10158080;         // 64*512*16
    float* feats = P;                     // reuse after scan (4096*256)
    float* carry = ws + 10682368;         // 64*512*16
    float* y     = ws + 11206656;         // 4096*512
    float* comb  = y;                     // reuse after out_proj (4096*264)
    float* h1    = h;                     // reuse (4096*128)
    float* h2    = h + 524288;            // (4096*128)

    // ---- Mamba block ----
    rmsnorm_k<<<4096, 256, 0, stream>>>(features, norm_w, h);
    gemm_mfma<<<dim3(64, 16), 256, 0, stream>>>(h, 256, in_proj_W, 256, xz, 1024,
                                                4096, 1024, 256, nullptr, nullptr, 0);
    conv_silu<<<8192, 256, 0, stream>>>(xz, conv_W, conv_b, xc);
    gemm_mfma<<<dim3(64, 1), 256, 0, stream>>>(xc, 512, x_proj_W, 512, dbc, 48,
                                               4096, 48, 512, nullptr, nullptr, 0);
    gemm_mfma<<<dim3(64, 8), 256, 0, stream>>>(dbc, 48, dt_proj_W, 16, delta, 512,
                                               4096, 512, 16, dt_proj_b, nullptr, 2);
    scan_phaseA<<<dim3(64, 32), 256, 0, stream>>>(delta, xc, dbc, A_log, P, S);
    scan_phaseB<<<32, 256, 0, stream>>>(P, S, carry);
    scan_phaseC<<<dim3(64, 32), 256, 0, stream>>>(delta, xc, dbc, A_log, carry, xz, Dp, y);
    gemm_mfma<<<dim3(64, 4), 256, 0, stream>>>(y, 512, out_proj_W, 512, outp, 256,
                                               4096, 256, 512, nullptr, features, 0);
    rmsnorm_k<<<4096, 256, 0, stream>>>(outp, norm_f_w, xf);
    gemm_mfma<<<dim3(64, 4), 256, 0, stream>>>(xf, 256, lm_head_W, 256, feats, 256,
                                               4096, 256, 256, nullptr, nullptr, 0);

    // ---- policy MLP steps ----
    softmax_pack<<<4224, 256, 0, stream>>>(feats, y_init, comb);
    for (int s = 0; s < 3; s++) {
        gemm_mfma<<<dim3(64, 2), 256, 0, stream>>>(comb, 264, fn1_W, 263, h1, 128,
                                                   4096, 128, 263, fn1_b, nullptr, 1);
        gemm_mfma<<<dim3(64, 2), 256, 0, stream>>>(h1, 128, fn2_W, 128, h2, 128,
                                                   4096, 128, 128, fn2_b, nullptr, 1);
        mlp_update<<<112, 256, 0, stream>>>(h2, mu_W, mu_b, var_W, var_b, eps, comb, out, s);
    }
}

// Round 3
// 340.020 us; speedup vs baseline: 1.8006x; 1.1174x over previous
//
#include <hip/hip_runtime.h>
#include <hip/hip_bf16.h>

// Mamba block (B=1, L=4096, D=256, d_inner=512, d_state=16, dt_rank=16, d_conv=4)
// + 3 sequential policy-MLP steps. fp32 in/out; GEMMs internally bf16-MFMA.
// Scan: 128 chunks x 32 steps, thread-per-d with 16 n-states in registers.

#define NCH  128
#define CLEN 32

typedef __bf16 bf16_t;
typedef __attribute__((ext_vector_type(8))) __bf16 bf16x8;
typedef __attribute__((ext_vector_type(4))) float f32x4;

__device__ __forceinline__ float softplus_f(float x) {
    return fmaxf(x, 0.f) + log1pf(__expf(-fabsf(x)));
}

// ---------------- rmsnorm: one block per row, D=256 ----------------
__global__ __launch_bounds__(256) void rmsnorm_k(const float* __restrict__ x,
                                                 const float* __restrict__ w,
                                                 float* __restrict__ o) {
    __shared__ float red[256];
    int row = blockIdx.x, t = threadIdx.x;
    float v = x[row * 256 + t];
    red[t] = v * v;
    __syncthreads();
    for (int s = 128; s > 0; s >>= 1) {
        if (t < s) red[t] += red[t + s];
        __syncthreads();
    }
    float rms = rsqrtf(red[0] / 256.f + 1e-5f);
    o[row * 256 + t] = v * rms * w[t];
}

// ---------------- bf16-MFMA GEMM: C[M,N] = act(A[M,K]*B[N,K]^T + bias + res) ----------------
#define TM 64
#define TN 64
#define TK 32
#define LDSS 40
__global__ __launch_bounds__(256) void gemm_mfma(
    const float* __restrict__ A, int lda,
    const float* __restrict__ B, int ldb,
    float* __restrict__ C, int ldc,
    int M, int N, int K,
    const float* __restrict__ bias,
    const float* __restrict__ res,
    int act)  // 0=none, 1=leaky_relu(0.1), 2=softplus
{
    __shared__ __align__(16) bf16_t As[TM * LDSS];
    __shared__ __align__(16) bf16_t Bs[TN * LDSS];
    int t = threadIdx.x;
    int lane = t & 63, wave = t >> 6;
    int wm = wave & 1, wn = wave >> 1;
    int fr = lane & 15;
    int quad = lane >> 4;
    int sr = t >> 2;
    int sc = t & 3;
    int m0 = blockIdx.x * TM, n0 = blockIdx.y * TN;

    f32x4 acc[2][2] = {};

    for (int k0 = 0; k0 < K; k0 += TK) {
        {
            int gm = m0 + sr;
            long base = (long)gm * lda + k0 + sc * 8;
            float v[8];
            if (gm < M && (k0 + sc * 8 + 8) <= K) {
                float4 p0 = *(const float4*)(A + base);
                float4 p1 = *(const float4*)(A + base + 4);
                v[0]=p0.x; v[1]=p0.y; v[2]=p0.z; v[3]=p0.w;
                v[4]=p1.x; v[5]=p1.y; v[6]=p1.z; v[7]=p1.w;
            } else {
#pragma unroll
                for (int j = 0; j < 8; j++) {
                    int gk = k0 + sc * 8 + j;
                    v[j] = (gm < M && gk < K) ? A[(long)gm * lda + gk] : 0.f;
                }
            }
            bf16x8 pk;
#pragma unroll
            for (int j = 0; j < 8; j++) pk[j] = (bf16_t)v[j];
            *(bf16x8*)&As[sr * LDSS + sc * 8] = pk;
        }
        {
            int gn = n0 + sr;
            long base = (long)gn * ldb + k0 + sc * 8;
            float v[8];
            if (gn < N && (k0 + sc * 8 + 8) <= K) {
                float4 p0 = *(const float4*)(B + base);
                float4 p1 = *(const float4*)(B + base + 4);
                v[0]=p0.x; v[1]=p0.y; v[2]=p0.z; v[3]=p0.w;
                v[4]=p1.x; v[5]=p1.y; v[6]=p1.z; v[7]=p1.w;
            } else {
#pragma unroll
                for (int j = 0; j < 8; j++) {
                    int gk = k0 + sc * 8 + j;
                    v[j] = (gn < N && gk < K) ? B[(long)gn * ldb + gk] : 0.f;
                }
            }
            bf16x8 pk;
#pragma unroll
            for (int j = 0; j < 8; j++) pk[j] = (bf16_t)v[j];
            *(bf16x8*)&Bs[sr * LDSS + sc * 8] = pk;
        }
        __syncthreads();
        bf16x8 af0 = *(bf16x8*)&As[(wm * 32 + fr) * LDSS + quad * 8];
        bf16x8 af1 = *(bf16x8*)&As[(wm * 32 + 16 + fr) * LDSS + quad * 8];
        bf16x8 bf0 = *(bf16x8*)&Bs[(wn * 32 + fr) * LDSS + quad * 8];
        bf16x8 bf1 = *(bf16x8*)&Bs[(wn * 32 + 16 + fr) * LDSS + quad * 8];
        acc[0][0] = __builtin_amdgcn_mfma_f32_16x16x32_bf16(af0, bf0, acc[0][0], 0, 0, 0);
        acc[0][1] = __builtin_amdgcn_mfma_f32_16x16x32_bf16(af0, bf1, acc[0][1], 0, 0, 0);
        acc[1][0] = __builtin_amdgcn_mfma_f32_16x16x32_bf16(af1, bf0, acc[1][0], 0, 0, 0);
        acc[1][1] = __builtin_amdgcn_mfma_f32_16x16x32_bf16(af1, bf1, acc[1][1], 0, 0, 0);
        __syncthreads();
    }

#pragma unroll
    for (int mi = 0; mi < 2; mi++) {
#pragma unroll
        for (int ni = 0; ni < 2; ni++) {
#pragma unroll
            for (int r = 0; r < 4; r++) {
                int m = m0 + wm * 32 + mi * 16 + quad * 4 + r;
                int n = n0 + wn * 32 + ni * 16 + fr;
                if (m < M && n < N) {
                    float v = acc[mi][ni][r];
                    if (bias) v += bias[n];
                    if (res)  v += res[(long)m * ldc + n];
                    if (act == 1) v = v > 0.f ? v : 0.1f * v;
                    else if (act == 2) v = softplus_f(v);
                    C[(long)m * ldc + n] = v;
                }
            }
        }
    }
}

// ---------------- causal depthwise conv (d_conv=4) + silu ----------------
__global__ __launch_bounds__(256) void conv_silu(const float* __restrict__ xz,
                                                 const float* __restrict__ W,
                                                 const float* __restrict__ b,
                                                 float* __restrict__ xc) {
    int t = blockIdx.x * 256 + threadIdx.x;
    int l = t >> 9, e = t & 511;
    float acc = b[e];
#pragma unroll
    for (int k = 0; k < 4; k++) {
        int ll = l - 3 + k;
        float xv = (ll >= 0) ? xz[ll * 1024 + e] : 0.f;
        acc += W[e * 4 + k] * xv;
    }
    float sig = 1.f / (1.f + __expf(-acc));
    xc[t] = acc * sig;
}

// ---------------- scan phase A: per (d, chunk): local final state + dt-sum ----------------
__global__ __launch_bounds__(256) void scanA(const float* __restrict__ delta,
                                             const float* __restrict__ xc,
                                             const float* __restrict__ dbc,
                                             const float* __restrict__ A_log,
                                             float* __restrict__ S,
                                             float* __restrict__ Tsum) {
    int d = blockIdx.x * 256 + threadIdx.x;   // 0..511
    int c = blockIdx.y;                        // 0..NCH-1
    float Ad[16];
#pragma unroll
    for (int j = 0; j < 4; j++) {
        float4 al = *(const float4*)&A_log[d * 16 + j * 4];
        Ad[j*4+0] = -__expf(al.x); Ad[j*4+1] = -__expf(al.y);
        Ad[j*4+2] = -__expf(al.z); Ad[j*4+3] = -__expf(al.w);
    }
    float s[16] = {};
    float ts = 0.f;
#pragma unroll 4
    for (int i = 0; i < CLEN; i++) {
        int l = c * CLEN + i;
        float dt = delta[l * 512 + d];
        float xv = xc[l * 512 + d];
        const float4* bp = (const float4*)&dbc[l * 48 + 16];
        float4 b0 = bp[0], b1 = bp[1], b2 = bp[2], b3 = bp[3];
        float bb[16] = {b0.x,b0.y,b0.z,b0.w, b1.x,b1.y,b1.z,b1.w,
                        b2.x,b2.y,b2.z,b2.w, b3.x,b3.y,b3.z,b3.w};
        float w = dt * xv;
        ts += dt;
#pragma unroll
        for (int n = 0; n < 16; n++) {
            float a = __expf(dt * Ad[n]);
            s[n] = a * s[n] + w * bb[n];
        }
    }
    long base = ((long)c * 512 + d) * 16;
#pragma unroll
    for (int j = 0; j < 4; j++)
        *(float4*)&S[base + j * 4] = make_float4(s[j*4], s[j*4+1], s[j*4+2], s[j*4+3]);
    Tsum[c * 512 + d] = ts;
}

// ---------------- scan phase B: sequential combine over chunks ----------------
__global__ __launch_bounds__(256) void scanB(const float* __restrict__ S,
                                             const float* __restrict__ Tsum,
                                             const float* __restrict__ A_log,
                                             float* __restrict__ carry) {
    int t = blockIdx.x * 256 + threadIdx.x;   // d*16+n, 0..8191
    int d = t >> 4;
    float Ad = -__expf(A_log[t]);
    float h = 0.f;
#pragma unroll 4
    for (int c = 0; c < NCH; c++) {
        carry[c * 8192 + t] = h;
        float p = __expf(Ad * Tsum[c * 512 + d]);
        h = p * h + S[c * 8192 + t];
    }
}

// ---------------- scan phase C: replay with carry, in-register n-reduction ----------------
__global__ __launch_bounds__(256) void scanC(const float* __restrict__ delta,
                                             const float* __restrict__ xc,
                                             const float* __restrict__ dbc,
                                             const float* __restrict__ A_log,
                                             const float* __restrict__ carry,
                                             const float* __restrict__ xz,
                                             const float* __restrict__ Dp,
                                             float* __restrict__ y) {
    int d = blockIdx.x * 256 + threadIdx.x;
    int c = blockIdx.y;
    float Ad[16];
#pragma unroll
    for (int j = 0; j < 4; j++) {
        float4 al = *(const float4*)&A_log[d * 16 + j * 4];
        Ad[j*4+0] = -__expf(al.x); Ad[j*4+1] = -__expf(al.y);
        Ad[j*4+2] = -__expf(al.z); Ad[j*4+3] = -__expf(al.w);
    }
    float s[16];
    long cbase = ((long)c * 512 + d) * 16;
#pragma unroll
    for (int j = 0; j < 4; j++) {
        float4 cv = *(const float4*)&carry[cbase + j * 4];
        s[j*4+0] = cv.x; s[j*4+1] = cv.y; s[j*4+2] = cv.z; s[j*4+3] = cv.w;
    }
    float dp = Dp[d];
#pragma unroll 4
    for (int i = 0; i < CLEN; i++) {
        int l = c * CLEN + i;
        float dt = delta[l * 512 + d];
        float xv = xc[l * 512 + d];
        const float4* bp = (const float4*)&dbc[l * 48 + 16];
        float4 b0 = bp[0], b1 = bp[1], b2 = bp[2], b3 = bp[3];
        float4 c0 = bp[4], c1 = bp[5], c2 = bp[6], c3 = bp[7];
        float bb[16] = {b0.x,b0.y,b0.z,b0.w, b1.x,b1.y,b1.z,b1.w,
                        b2.x,b2.y,b2.z,b2.w, b3.x,b3.y,b3.z,b3.w};
        float cc[16] = {c0.x,c0.y,c0.z,c0.w, c1.x,c1.y,c1.z,c1.w,
                        c2.x,c2.y,c2.z,c2.w, c3.x,c3.y,c3.z,c3.w};
        float w = dt * xv;
        float acc = xv * dp;
#pragma unroll
        for (int n = 0; n < 16; n++) {
            float a = __expf(dt * Ad[n]);
            s[n] = a * s[n] + w * bb[n];
            acc += s[n] * cc[n];
        }
        float z = xz[l * 1024 + 512 + d];
        float sig = 1.f / (1.f + __expf(-z));
        y[l * 512 + d] = acc * (z * sig);
    }
}

// ---------------- softmax(y_init) + pack combined = [feats | y_t] (stride 264) ----------------
__global__ __launch_bounds__(256) void softmax_pack(const float* __restrict__ feats,
                                                    const float* __restrict__ logits,
                                                    float* __restrict__ comb) {
    int t = blockIdx.x * 256 + threadIdx.x;
    int row = t / 264, col = t % 264;
    if (col < 256) {
        comb[row * 264 + col] = feats[row * 256 + col];
    } else if (col < 263) {
        int c = col - 256;
        float v[7], m = -1e30f;
#pragma unroll
        for (int i = 0; i < 7; i++) { v[i] = logits[row * 7 + i]; m = fmaxf(m, v[i]); }
        float sum = 0.f;
#pragma unroll
        for (int i = 0; i < 7; i++) sum += __expf(v[i] - m);
        comb[row * 264 + col] = __expf(v[c] - m) / sum;
    }
}

// ---------------- pack [muW; varW] into one 14x128 weight ----------------
__global__ __launch_bounds__(256) void pack_pw(const float* __restrict__ muW,
                                               const float* __restrict__ varW,
                                               float* __restrict__ pw) {
    int t = blockIdx.x * 256 + threadIdx.x;
    if (t < 896) pw[t] = muW[t];
    else if (t < 1792) pw[t] = varW[t - 896];
}

// ---------------- elementwise action update from mv = [mu | var_pre] ----------------
__global__ __launch_bounds__(256) void mlp_update2(const float* __restrict__ mv,
                                                   const float* __restrict__ mub,
                                                   const float* __restrict__ varb,
                                                   const float* __restrict__ eps,
                                                   float* __restrict__ comb,
                                                   float* __restrict__ out,
                                                   int step) {
    int t = blockIdx.x * 256 + threadIdx.x;
    if (t >= 4096 * 7) return;
    int row = t / 7, c = t % 7;
    float mu = mv[row * 14 + c] + mub[c];
    float sp = softplus_f(mv[row * 14 + 7 + c] + varb[c]);
    float e = eps[(step * 4096 + row) * 7 + c];
    float yo = comb[row * 264 + 256 + c];
    float yn = yo - (mu + sp * e);
    out[(step * 4096 + row) * 7 + c] = yn;
    comb[row * 264 + 256 + c] = yn;
}

extern "C" void kernel_launch(void* const* d_in, const int* in_sizes, int n_in,
                              void* d_out, int out_size, void* d_ws, size_t ws_size,
                              hipStream_t stream) {
    const float* features  = (const float*)d_in[0];
    const float* y_init    = (const float*)d_in[1];
    const float* eps       = (const float*)d_in[2];
    const float* in_proj_W = (const float*)d_in[3];
    const float* conv_W    = (const float*)d_in[4];
    const float* conv_b    = (const float*)d_in[5];
    const float* x_proj_W  = (const float*)d_in[6];
    const float* dt_proj_W = (const float*)d_in[7];
    const float* dt_proj_b = (const float*)d_in[8];
    const float* A_log     = (const float*)d_in[9];
    const float* Dp        = (const float*)d_in[10];
    const float* out_proj_W= (const float*)d_in[11];
    const float* norm_w    = (const float*)d_in[12];
    const float* norm_f_w  = (const float*)d_in[13];
    const float* lm_head_W = (const float*)d_in[14];
    const float* fn1_W     = (const float*)d_in[15];
    const float* fn1_b     = (const float*)d_in[16];
    const float* fn2_W     = (const float*)d_in[17];
    const float* fn2_b     = (const float*)d_in[18];
    const float* mu_W      = (const float*)d_in[19];
    const float* mu_b      = (const float*)d_in[20];
    const float* var_W     = (const float*)d_in[21];
    const float* var_b     = (const float*)d_in[22];
    float* out = (float*)d_out;
    float* ws  = (float*)d_ws;

    // workspace layout (floats); max offset 12,779,520 (51.1 MB)
    float* h     = ws;                    // 4096*256      [carry reuses after in_proj]
    float* xz    = ws + 1048576;          // 4096*1024     [comb reuses after scanC]
    float* xc    = ws + 5242880;          // 4096*512      [h1/h2 reuse after scanC]
    float* dbc   = ws + 7340032;          // 4096*48       [mv, pw reuse after scanC]
    float* delta = ws + 7536640;          // 4096*512      [outp, feats reuse after scanC]
    float* xf    = ws + 9633792;          // 4096*256      [Tsum reuses before]
    float* y     = ws + 10682368;         // 4096*512      [S reuses before scanC]
    float* carry = h;                     // 128*512*16 = 1,048,576
    float* S     = y;                     // 128*512*16 = 1,048,576
    float* Tsum  = xf;                    // 128*512 = 65,536
    float* outp  = delta;                 // 4096*256
    float* feats = delta + 1048576;       // 4096*256
    float* comb  = xz;                    // 4096*264
    float* h1    = xc;                    // 4096*128
    float* h2    = xc + 524288;           // 4096*128
    float* mv    = dbc;                   // 4096*14
    float* pw    = dbc + 131072;          // 14*128

    // ---- Mamba block ----
    rmsnorm_k<<<4096, 256, 0, stream>>>(features, norm_w, h);
    gemm_mfma<<<dim3(64, 16), 256, 0, stream>>>(h, 256, in_proj_W, 256, xz, 1024,
                                                4096, 1024, 256, nullptr, nullptr, 0);
    conv_silu<<<8192, 256, 0, stream>>>(xz, conv_W, conv_b, xc);
    gemm_mfma<<<dim3(64, 1), 256, 0, stream>>>(xc, 512, x_proj_W, 512, dbc, 48,
                                               4096, 48, 512, nullptr, nullptr, 0);
    gemm_mfma<<<dim3(64, 8), 256, 0, stream>>>(dbc, 48, dt_proj_W, 16, delta, 512,
                                               4096, 512, 16, dt_proj_b, nullptr, 2);
    scanA<<<dim3(2, NCH), 256, 0, stream>>>(delta, xc, dbc, A_log, S, Tsum);
    scanB<<<32, 256, 0, stream>>>(S, Tsum, A_log, carry);
    scanC<<<dim3(2, NCH), 256, 0, stream>>>(delta, xc, dbc, A_log, carry, xz, Dp, y);
    gemm_mfma<<<dim3(64, 4), 256, 0, stream>>>(y, 512, out_proj_W, 512, outp, 256,
                                               4096, 256, 512, nullptr, features, 0);
    rmsnorm_k<<<4096, 256, 0, stream>>>(outp, norm_f_w, xf);
    gemm_mfma<<<dim3(64, 4), 256, 0, stream>>>(xf, 256, lm_head_W, 256, feats, 256,
                                               4096, 256, 256, nullptr, nullptr, 0);

    // ---- policy MLP steps ----
    softmax_pack<<<4224, 256, 0, stream>>>(feats, y_init, comb);
    pack_pw<<<7, 256, 0, stream>>>(mu_W, var_W, pw);
    for (int s = 0; s < 3; s++) {
        gemm_mfma<<<dim3(64, 2), 256, 0, stream>>>(comb, 264, fn1_W, 263, h1, 128,
                                                   4096, 128, 263, fn1_b, nullptr, 1);
        gemm_mfma<<<dim3(64, 2), 256, 0, stream>>>(h1, 128, fn2_W, 128, h2, 128,
                                                   4096, 128, 128, fn2_b, nullptr, 1);
        gemm_mfma<<<dim3(64, 1), 256, 0, stream>>>(h2, 128, pw, 128, mv, 14,
                                                   4096, 14, 128, nullptr, nullptr, 0);
        mlp_update2<<<112, 256, 0, stream>>>(mv, mu_b, var_b, eps, comb, out, s);
    }
}